// Round 4
// baseline (870.143 us; speedup 1.0000x reference)
//
#include <hip/hip_runtime.h>
#include <hip/hip_bf16.h>
#include <math.h>

#define DD 256
#define HH 128
#define OO 64

#define EPB 8192          // edges per partition block
#define BKT 512           // nodes per bucket (bucket = idx >> 9)

typedef __attribute__((ext_vector_type(8))) __bf16 bf16x8;
typedef __attribute__((ext_vector_type(4))) __bf16 bf16x4;
typedef __attribute__((ext_vector_type(4))) float f32x4;

// ---------------------------------------------------------------------------
// K1: per-block LDS histograms over coarse buckets (both col and row sides)
// ---------------------------------------------------------------------------
__global__ void part_count_kernel(const int* __restrict__ row, const int* __restrict__ col,
                                  int e, int nb,
                                  int* __restrict__ cnt_col, int* __restrict__ cnt_row) {
    __shared__ int hc[256], hr[256];
    int t = threadIdx.x;
    hc[t] = 0; hr[t] = 0;
    __syncthreads();
    int base = blockIdx.x * EPB;
    int lim  = min(EPB, e - base);
    for (int i = t; i < lim; i += 256) {
        atomicAdd(&hc[col[base + i] >> 9], 1);
        atomicAdd(&hr[row[base + i] >> 9], 1);
    }
    __syncthreads();
    if (t < nb) {
        cnt_col[blockIdx.x * nb + t] = hc[t];
        cnt_row[blockIdx.x * nb + t] = hr[t];
    }
}

// ---------------------------------------------------------------------------
// K2: single block. Per-(block,bucket) exclusive bases + bucket totals/bases.
// Requires nb <= 256. Also writes row_ptr[n] = e.
// ---------------------------------------------------------------------------
__global__ void part_scan_kernel(const int* __restrict__ cnt_col, const int* __restrict__ cnt_row,
                                 int* __restrict__ base_col, int* __restrict__ base_row,
                                 int* __restrict__ bb_col, int* __restrict__ tot_col,
                                 int* __restrict__ bb_row, int* __restrict__ tot_row,
                                 int* __restrict__ row_ptr, int n, int e, int nblk, int nb) {
    __shared__ int s[256];
    int t = threadIdx.x;

    // ---- col side ----
    int run = 0;
    if (t < nb)
        for (int blk = 0; blk < nblk; ++blk) {
            base_col[blk * nb + t] = run;
            run += cnt_col[blk * nb + t];
        }
    int total = (t < nb) ? run : 0;
    s[t] = total;
    __syncthreads();
    for (int off = 1; off < 256; off <<= 1) {
        int v = (t >= off) ? s[t - off] : 0;
        __syncthreads();
        s[t] += v;
        __syncthreads();
    }
    int bbase = s[t] - total;
    if (t < nb) {
        bb_col[t]  = bbase;
        tot_col[t] = total;
        for (int blk = 0; blk < nblk; ++blk) base_col[blk * nb + t] += bbase;
    }
    __syncthreads();

    // ---- row side ----
    run = 0;
    if (t < nb)
        for (int blk = 0; blk < nblk; ++blk) {
            base_row[blk * nb + t] = run;
            run += cnt_row[blk * nb + t];
        }
    total = (t < nb) ? run : 0;
    s[t] = total;
    __syncthreads();
    for (int off = 1; off < 256; off <<= 1) {
        int v = (t >= off) ? s[t - off] : 0;
        __syncthreads();
        s[t] += v;
        __syncthreads();
    }
    bbase = s[t] - total;
    if (t < nb) {
        bb_row[t]  = bbase;
        tot_row[t] = total;
        for (int blk = 0; blk < nblk; ++blk) base_row[blk * nb + t] += bbase;
    }
    if (t == 0) row_ptr[n] = e;
}

// ---------------------------------------------------------------------------
// K3: scatter edges into bucket-major temps via LDS cursors (no global atomics)
// tmp_col: int4 (col, row, ppmi_bits, 0); tmp_row: int2 (row, ppmi_bits)
// ---------------------------------------------------------------------------
__global__ void part_scatter_kernel(const int* __restrict__ row, const int* __restrict__ col,
                                    const float* __restrict__ ppmi,
                                    const int* __restrict__ base_col, const int* __restrict__ base_row,
                                    int4* __restrict__ tmp_col, int2* __restrict__ tmp_row,
                                    int e, int nb) {
    __shared__ int cc[256], cr[256];
    int t = threadIdx.x;
    if (t < nb) {
        cc[t] = base_col[blockIdx.x * nb + t];
        cr[t] = base_row[blockIdx.x * nb + t];
    }
    __syncthreads();
    int base = blockIdx.x * EPB;
    int lim  = min(EPB, e - base);
    for (int i = t; i < lim; i += 256) {
        int r = row[base + i], c = col[base + i];
        int w = __float_as_int(ppmi[base + i]);
        int sc = atomicAdd(&cc[c >> 9], 1);
        tmp_col[sc] = make_int4(c, r, w, 0);
        int sr = atomicAdd(&cr[r >> 9], 1);
        tmp_row[sr] = make_int2(r, w);
    }
}

// ---------------------------------------------------------------------------
// K4b: per-row-bucket degree accumulation in LDS (float LDS atomics), -> dis
// ---------------------------------------------------------------------------
__global__ void deg_bucket_kernel(const int2* __restrict__ tmp_row,
                                  const int* __restrict__ bb_row, const int* __restrict__ tot_row,
                                  float* __restrict__ dis_g, float* __restrict__ dis_p, int n) {
    __shared__ float dg[BKT], dp[BKT];
    int t = threadIdx.x;
    for (int j = t; j < BKT; j += 256) { dg[j] = 1.0f; dp[j] = 1.0f; }  // self-loop
    __syncthreads();
    int b = blockIdx.x;
    int beg = bb_row[b], cnt = tot_row[b];
    for (int i = t; i < cnt; i += 256) {
        int2 cell = tmp_row[beg + i];
        int lr = cell.x & (BKT - 1);
        atomicAdd(&dg[lr], 1.0f);
        atomicAdd(&dp[lr], __int_as_float(cell.y));
    }
    __syncthreads();
    int rb = b << 9;
    for (int j = t; j < BKT; j += 256) {
        int g = rb + j;
        if (g < n) {
            dis_g[g] = rsqrtf(dg[j]);
            dis_p[g] = rsqrtf(dp[j]);
        }
    }
}

// ---------------------------------------------------------------------------
// K4: per-col-bucket CSR finalize: LDS hist + scan -> row_ptr, LDS cursors ->
// csr fill with weights (dis gathers are L2-resident). 512 threads.
// ---------------------------------------------------------------------------
__launch_bounds__(512)
__global__ void csr_bucket_kernel(const int4* __restrict__ tmp_col,
                                  const int* __restrict__ bb_col, const int* __restrict__ tot_col,
                                  const float* __restrict__ dis_g, const float* __restrict__ dis_p,
                                  int* __restrict__ row_ptr, int* __restrict__ csr_src,
                                  float* __restrict__ csr_wg, float* __restrict__ csr_wp, int n) {
    __shared__ int hist[BKT], s[BKT], cur[BKT];
    int t = threadIdx.x;   // 512 threads
    hist[t] = 0;
    __syncthreads();
    int b = blockIdx.x;
    int beg = bb_col[b], cnt = tot_col[b];
    for (int i = t; i < cnt; i += BKT) atomicAdd(&hist[tmp_col[beg + i].x & (BKT - 1)], 1);
    __syncthreads();
    int own = hist[t];
    s[t] = own;
    __syncthreads();
    for (int off = 1; off < BKT; off <<= 1) {
        int v = (t >= off) ? s[t - off] : 0;
        __syncthreads();
        s[t] += v;
        __syncthreads();
    }
    int gslot = beg + s[t] - own;     // global CSR slot base for local col t
    cur[t] = gslot;
    int gc = (b << 9) + t;
    if (gc < n) row_ptr[gc] = gslot;
    __syncthreads();
    for (int i = t; i < cnt; i += BKT) {
        int4 cell = tmp_col[beg + i];
        int lc = cell.x & (BKT - 1);
        int slot = atomicAdd(&cur[lc], 1);
        int r = cell.y;
        float w = __int_as_float(cell.z);
        csr_src[slot] = r;
        csr_wg[slot]  = dis_g[r];
        csr_wp[slot]  = dis_p[r] * w;
    }
}

// ---------------------------------------------------------------------------
// W -> B^T split-bf16 prep
// ---------------------------------------------------------------------------
__global__ void conv_w_kernel(const float* __restrict__ W, __bf16* __restrict__ Bh,
                              __bf16* __restrict__ Bl, int K, int N) {
    int i = blockIdx.x * blockDim.x + threadIdx.x;
    if (i >= K * N) return;
    int k = i / N, nn = i % N;
    float v = W[i];
    __bf16 h = (__bf16)v;
    Bh[(size_t)nn * K + k] = h;
    Bl[(size_t)nn * K + k] = (__bf16)(v - (float)h);
}

// ---------------------------------------------------------------------------
// Split-bf16 MFMA GEMM: C[M,BN] = A[M,K] @ B[K,BN]
// ---------------------------------------------------------------------------
template<int BM, int BN>
__launch_bounds__(256, 2)
__global__ void mfma_gemm_kernel(const float* __restrict__ A,
                                 const __bf16* __restrict__ Bth, const __bf16* __restrict__ Btl,
                                 float* __restrict__ C, int M, int K) {
    constexpr int BK  = 32;
    constexpr int LDK = BK + 8;
    constexpr int WM  = BM / 4;
    constexpr int MT  = WM / 16;
    constexpr int NT  = BN / 16;
    __shared__ __bf16 Ash[BM * LDK];
    __shared__ __bf16 Asl[BM * LDK];
    __shared__ __bf16 Bsh[BN * LDK];
    __shared__ __bf16 Bsl[BN * LDK];

    const int tid  = threadIdx.x;
    const int wave = tid >> 6;
    const int lane = tid & 63;
    const int quad = lane >> 4;
    const int l16  = lane & 15;
    const int row0 = blockIdx.x * BM;

    f32x4 acc[MT][NT] = {};

    for (int k0 = 0; k0 < K; k0 += BK) {
#pragma unroll
        for (int p = 0; p < BM / 32; ++p) {
            int lin = p * 256 + tid;
            int r   = lin >> 3;
            int kc  = (lin & 7) * 4;
            int gr  = row0 + r;
            float4 v;
            if (gr < M) v = *(const float4*)(A + (size_t)gr * K + k0 + kc);
            else        v = make_float4(0.f, 0.f, 0.f, 0.f);
            __bf16 h0 = (__bf16)v.x, h1 = (__bf16)v.y, h2 = (__bf16)v.z, h3 = (__bf16)v.w;
            __bf16 l0 = (__bf16)(v.x - (float)h0), l1 = (__bf16)(v.y - (float)h1);
            __bf16 l2 = (__bf16)(v.z - (float)h2), l3 = (__bf16)(v.w - (float)h3);
            *(bf16x4*)&Ash[r * LDK + kc] = (bf16x4){h0, h1, h2, h3};
            *(bf16x4*)&Asl[r * LDK + kc] = (bf16x4){l0, l1, l2, l3};
        }
#pragma unroll
        for (int p = 0; p < BN / 64; ++p) {
            int lin = p * 256 + tid;
            int r   = lin >> 2;
            int kc  = (lin & 3) * 8;
            *(uint4*)&Bsh[r * LDK + kc] = *(const uint4*)(Bth + (size_t)r * K + k0 + kc);
            *(uint4*)&Bsl[r * LDK + kc] = *(const uint4*)(Btl + (size_t)r * K + k0 + kc);
        }
        __syncthreads();

        bf16x8 bh[NT], bl[NT];
#pragma unroll
        for (int j = 0; j < NT; ++j) {
            bh[j] = *(const bf16x8*)&Bsh[(j * 16 + l16) * LDK + quad * 8];
            bl[j] = *(const bf16x8*)&Bsl[(j * 16 + l16) * LDK + quad * 8];
        }
#pragma unroll
        for (int i = 0; i < MT; ++i) {
            int m = wave * WM + i * 16 + l16;
            bf16x8 ah = *(const bf16x8*)&Ash[m * LDK + quad * 8];
            bf16x8 al = *(const bf16x8*)&Asl[m * LDK + quad * 8];
#pragma unroll
            for (int j = 0; j < NT; ++j) {
                acc[i][j] = __builtin_amdgcn_mfma_f32_16x16x32_bf16(ah, bh[j], acc[i][j], 0, 0, 0);
                acc[i][j] = __builtin_amdgcn_mfma_f32_16x16x32_bf16(ah, bl[j], acc[i][j], 0, 0, 0);
                acc[i][j] = __builtin_amdgcn_mfma_f32_16x16x32_bf16(al, bh[j], acc[i][j], 0, 0, 0);
            }
        }
        __syncthreads();
    }

#pragma unroll
    for (int i = 0; i < MT; ++i) {
#pragma unroll
        for (int rg = 0; rg < 4; ++rg) {
            int gr = row0 + wave * WM + i * 16 + quad * 4 + rg;
            if (gr < M) {
#pragma unroll
                for (int j = 0; j < NT; ++j)
                    C[(size_t)gr * BN + j * 16 + l16] = acc[i][j][rg];
            }
        }
    }
}

// ---------------------------------------------------------------------------
// Layer-1 pull aggregation: one wave per node, float2 per lane (128 feats).
// ---------------------------------------------------------------------------
__global__ void agg1_pull_kernel(const int* __restrict__ row_ptr, const int* __restrict__ csr_src,
                                 const float* __restrict__ csr_wg, const float* __restrict__ csr_wp,
                                 const float* __restrict__ hw1,
                                 const float* __restrict__ dis_g, const float* __restrict__ dis_p,
                                 const float* __restrict__ b1,
                                 float* __restrict__ g_out, float* __restrict__ p_out, int n) {
    int c    = blockIdx.x * 4 + (threadIdx.x >> 6);
    int lane = threadIdx.x & 63;
    if (c >= n) return;
    int beg = row_ptr[c], end = row_ptr[c + 1];
    int f2 = lane * 2;
    float sgx = 0.f, sgy = 0.f, spx = 0.f, spy = 0.f;
    int t = beg;
    for (; t + 2 <= end; t += 2) {
        int r0 = csr_src[t], r1 = csr_src[t + 1];
        float wg0 = csr_wg[t], wg1 = csr_wg[t + 1];
        float wp0 = csr_wp[t], wp1 = csr_wp[t + 1];
        float2 h0 = *(const float2*)&hw1[(size_t)r0 * HH + f2];
        float2 h1 = *(const float2*)&hw1[(size_t)r1 * HH + f2];
        sgx += wg0 * h0.x + wg1 * h1.x;
        sgy += wg0 * h0.y + wg1 * h1.y;
        spx += wp0 * h0.x + wp1 * h1.x;
        spy += wp0 * h0.y + wp1 * h1.y;
    }
    if (t < end) {
        int r0 = csr_src[t];
        float wg0 = csr_wg[t], wp0 = csr_wp[t];
        float2 h0 = *(const float2*)&hw1[(size_t)r0 * HH + f2];
        sgx += wg0 * h0.x; sgy += wg0 * h0.y;
        spx += wp0 * h0.x; spy += wp0 * h0.y;
    }
    float dgc = dis_g[c], dpc = dis_p[c];
    size_t idx = (size_t)c * HH + f2;
    float2 hs = *(const float2*)&hw1[idx];
    float bx = b1[f2], by = b1[f2 + 1];
    float gx = dgc * sgx + dgc * dgc * hs.x + bx;
    float gy = dgc * sgy + dgc * dgc * hs.y + by;
    float px = dpc * spx + dpc * dpc * hs.x + bx;
    float py = dpc * spy + dpc * dpc * hs.y + by;
    float2 go, po;
    go.x = gx > 0.f ? gx : 0.f;  go.y = gy > 0.f ? gy : 0.f;
    po.x = px > 0.f ? px : 0.f;  po.y = py > 0.f ? py : 0.f;
    *(float2*)&g_out[idx] = go;
    *(float2*)&p_out[idx] = po;
}

// ---------------------------------------------------------------------------
// Layer-2 pull aggregation + self-loop + bias + softmax gate, fused.
// ---------------------------------------------------------------------------
__global__ void agg2_final_kernel(const int* __restrict__ row_ptr, const int* __restrict__ csr_src,
                                  const float* __restrict__ csr_wg, const float* __restrict__ csr_wp,
                                  const float* __restrict__ hw2_g, const float* __restrict__ hw2_p,
                                  const float* __restrict__ dis_g, const float* __restrict__ dis_p,
                                  const float* __restrict__ b2,
                                  const float* __restrict__ dense_w, const float* __restrict__ dense_b,
                                  float* __restrict__ out, int n) {
    int c = blockIdx.x * 4 + (threadIdx.x >> 6);
    int f = threadIdx.x & 63;
    if (c >= n) return;
    int beg = row_ptr[c], end = row_ptr[c + 1];
    float sg = 0.f, sp = 0.f;
    int t = beg;
    for (; t + 2 <= end; t += 2) {
        int r0 = csr_src[t], r1 = csr_src[t + 1];
        float wg0 = csr_wg[t], wg1 = csr_wg[t + 1];
        float wp0 = csr_wp[t], wp1 = csr_wp[t + 1];
        float hg0 = hw2_g[(size_t)r0 * OO + f], hg1 = hw2_g[(size_t)r1 * OO + f];
        float hp0 = hw2_p[(size_t)r0 * OO + f], hp1 = hw2_p[(size_t)r1 * OO + f];
        sg += wg0 * hg0 + wg1 * hg1;
        sp += wp0 * hp0 + wp1 * hp1;
    }
    if (t < end) {
        int r0 = csr_src[t];
        sg += csr_wg[t] * hw2_g[(size_t)r0 * OO + f];
        sp += csr_wp[t] * hw2_p[(size_t)r0 * OO + f];
    }
    float dgc = dis_g[c], dpc = dis_p[c];
    size_t idx = (size_t)c * OO + f;
    float bb = b2[f];
    float gv = dgc * sg + dgc * dgc * hw2_g[idx] + bb;
    float pv = dpc * sp + dpc * dpc * hw2_p[idx] + bb;
    float dw = dense_w[f];
    float lg = gv * dw, lp = pv * dw;
#pragma unroll
    for (int off = 32; off > 0; off >>= 1) {
        lg += __shfl_xor(lg, off, 64);
        lp += __shfl_xor(lp, off, 64);
    }
    lg += dense_b[0];
    lp += dense_b[0];
    float m  = fmaxf(lg, lp);
    float eg = expf(lg - m), ep = expf(lp - m);
    float wgt = eg / (eg + ep);
    out[idx] = wgt * gv + (1.0f - wgt) * pv;
}

// ---------------------------------------------------------------------------
extern "C" void kernel_launch(void* const* d_in, const int* in_sizes, int n_in,
                              void* d_out, int out_size, void* d_ws, size_t ws_size,
                              hipStream_t stream) {
    const float* x    = (const float*)d_in[0];
    const int*   ei   = (const int*)d_in[1];
    const float* ppmi = (const float*)d_in[2];
    const float* W1   = (const float*)d_in[3];
    const float* b1   = (const float*)d_in[4];
    const float* W2   = (const float*)d_in[5];
    const float* b2   = (const float*)d_in[6];
    const float* dw   = (const float*)d_in[7];
    const float* db   = (const float*)d_in[8];
    float* out = (float*)d_out;

    const int n = in_sizes[0] / DD;       // 100000 (even -> 16B-aligned aliases below)
    const int e = in_sizes[2];            // 1600000
    const int* row = ei;
    const int* col = ei + e;

    const int nb   = (n + BKT - 1) / BKT;   // 196 buckets (<=256 required)
    const int nblk = (e + EPB - 1) / EPB;   // 196 partition blocks (<=256 required)

    // ---- workspace layout (floats unless noted) ----
    float* ws     = (float*)d_ws;
    float* dis_g  = ws;                              // n
    float* dis_p  = dis_g + n;                       // n
    float* hw1    = dis_p + n;                       // 128n (reused as hw2[2n*64])
    float* g1     = hw1 + (size_t)n * HH;            // 128n (tmp_col aliases: 4e ints)
    float* p1     = g1  + (size_t)n * HH;            // 128n (tmp_row aliases: 2e ints)
    float* csr_wg = p1  + (size_t)n * HH;            // e
    float* csr_wp = csr_wg + e;                      // e
    __bf16* bt1h  = (__bf16*)(csr_wp + e);           // DD*HH
    __bf16* bt1l  = bt1h + (size_t)DD * HH;
    __bf16* bt2h  = bt1l + (size_t)DD * HH;          // HH*OO
    __bf16* bt2l  = bt2h + (size_t)HH * OO;
    int* row_ptr  = (int*)(bt2l + (size_t)HH * OO);  // n+1
    int* csr_src  = row_ptr + (n + 1);               // e
    int* cnt_col  = csr_src + e;                     // nblk*nb
    int* base_col = cnt_col + (size_t)nblk * nb;     // nblk*nb
    int* cnt_row  = base_col + (size_t)nblk * nb;    // nblk*nb
    int* base_row = cnt_row + (size_t)nblk * nb;     // nblk*nb
    int* bb_col   = base_row + (size_t)nblk * nb;    // nb
    int* tot_col  = bb_col + nb;                     // nb
    int* bb_row   = tot_col + nb;                    // nb
    int* tot_row  = bb_row + nb;                     // nb
    int4* tmp_col = (int4*)g1;                       // e (alias, dead before agg1 writes g1)
    int2* tmp_row = (int2*)p1;                       // e (alias, dead before agg1 writes p1)
    float* hw2    = hw1;                             // [2n x 64]
    float* hw2_g  = hw2;
    float* hw2_p  = hw2 + (size_t)n * OO;

    const int T = 256;

    // ---- partition pipeline (LDS atomics only) ----
    part_count_kernel<<<nblk, T, 0, stream>>>(row, col, e, nb, cnt_col, cnt_row);
    part_scan_kernel<<<1, T, 0, stream>>>(cnt_col, cnt_row, base_col, base_row,
                                          bb_col, tot_col, bb_row, tot_row,
                                          row_ptr, n, e, nblk, nb);
    part_scatter_kernel<<<nblk, T, 0, stream>>>(row, col, ppmi, base_col, base_row,
                                                tmp_col, tmp_row, e, nb);
    deg_bucket_kernel<<<nb, T, 0, stream>>>(tmp_row, bb_row, tot_row, dis_g, dis_p, n);
    csr_bucket_kernel<<<nb, BKT, 0, stream>>>(tmp_col, bb_col, tot_col, dis_g, dis_p,
                                              row_ptr, csr_src, csr_wg, csr_wp, n);

    // ---- weight prep ----
    conv_w_kernel<<<(DD * HH + T - 1) / T, T, 0, stream>>>(W1, bt1h, bt1l, DD, HH);
    conv_w_kernel<<<(HH * OO + T - 1) / T, T, 0, stream>>>(W2, bt2h, bt2l, HH, OO);

    // ---- network ----
    mfma_gemm_kernel<128, HH><<<(n + 127) / 128, 256, 0, stream>>>(x, bt1h, bt1l, hw1, n, DD);
    agg1_pull_kernel<<<(n + 3) / 4, 256, 0, stream>>>(row_ptr, csr_src, csr_wg, csr_wp,
                                                      hw1, dis_g, dis_p, b1, g1, p1, n);
    mfma_gemm_kernel<128, OO><<<(2 * n + 127) / 128, 256, 0, stream>>>(g1, bt2h, bt2l, hw2, 2 * n, HH);
    agg2_final_kernel<<<(n + 3) / 4, 256, 0, stream>>>(row_ptr, csr_src, csr_wg, csr_wp,
                                                       hw2_g, hw2_p, dis_g, dis_p, b2, dw, db, out, n);
}

// Round 5
// 676.794 us; speedup vs baseline: 1.2857x; 1.2857x over previous
//
#include <hip/hip_runtime.h>
#include <hip/hip_bf16.h>
#include <math.h>

#define DD 256
#define HH 128
#define OO 64

#define EPB 8192          // edges per partition block
#define BKT 512           // nodes per bucket (bucket = idx >> 9)

typedef __attribute__((ext_vector_type(8))) __bf16 bf16x8;
typedef __attribute__((ext_vector_type(4))) __bf16 bf16x4;
typedef __attribute__((ext_vector_type(4))) float f32x4;

// ---------------------------------------------------------------------------
// K1: per-block LDS histograms over coarse buckets (both col and row sides)
// ---------------------------------------------------------------------------
__global__ void part_count_kernel(const int* __restrict__ row, const int* __restrict__ col,
                                  int e, int nb,
                                  int* __restrict__ cnt_col, int* __restrict__ cnt_row) {
    __shared__ int hc[256], hr[256];
    int t = threadIdx.x;
    hc[t] = 0; hr[t] = 0;
    __syncthreads();
    int base = blockIdx.x * EPB;
    int lim  = min(EPB, e - base);
    for (int i = t; i < lim; i += 256) {
        atomicAdd(&hc[col[base + i] >> 9], 1);
        atomicAdd(&hr[row[base + i] >> 9], 1);
    }
    __syncthreads();
    if (t < nb) {
        cnt_col[blockIdx.x * nb + t] = hc[t];
        cnt_row[blockIdx.x * nb + t] = hr[t];
    }
}

// ---------------------------------------------------------------------------
// K2a: one block per (side,bucket). Parallel scan over the nblk per-block
// counts of that bucket -> per-block bases (bucket-local) + bucket total.
// Requires nblk <= 256.
// ---------------------------------------------------------------------------
__global__ void scan_blocks_kernel(const int* __restrict__ cnt_col, const int* __restrict__ cnt_row,
                                   int* __restrict__ base_col, int* __restrict__ base_row,
                                   int* __restrict__ tot_col, int* __restrict__ tot_row,
                                   int nblk, int nb) {
    __shared__ int s[256];
    int side = (blockIdx.x >= (unsigned)nb) ? 1 : 0;
    int b = blockIdx.x - side * nb;
    const int* cnt = side ? cnt_row : cnt_col;
    int* base = side ? base_row : base_col;
    int* tot  = side ? tot_row  : tot_col;
    int t = threadIdx.x;
    int v = (t < nblk) ? cnt[(size_t)t * nb + b] : 0;
    s[t] = v;
    __syncthreads();
    for (int off = 1; off < 256; off <<= 1) {
        int u = (t >= off) ? s[t - off] : 0;
        __syncthreads();
        s[t] += u;
        __syncthreads();
    }
    if (t < nblk) base[(size_t)t * nb + b] = s[t] - v;
    if (t == 255) tot[b] = s[255];
}

// ---------------------------------------------------------------------------
// K2b: one block. Exclusive scan of both totals arrays -> bucket bases.
// Requires nb <= 256.
// ---------------------------------------------------------------------------
__global__ void scan_tots_kernel(const int* __restrict__ tot_col, const int* __restrict__ tot_row,
                                 int* __restrict__ bb_col, int* __restrict__ bb_row, int nb) {
    __shared__ int s[256];
    int t = threadIdx.x;
    int v = (t < nb) ? tot_col[t] : 0;
    s[t] = v;
    __syncthreads();
    for (int off = 1; off < 256; off <<= 1) {
        int u = (t >= off) ? s[t - off] : 0;
        __syncthreads();
        s[t] += u;
        __syncthreads();
    }
    if (t < nb) bb_col[t] = s[t] - v;
    __syncthreads();
    int v2 = (t < nb) ? tot_row[t] : 0;
    s[t] = v2;
    __syncthreads();
    for (int off = 1; off < 256; off <<= 1) {
        int u = (t >= off) ? s[t - off] : 0;
        __syncthreads();
        s[t] += u;
        __syncthreads();
    }
    if (t < nb) bb_row[t] = s[t] - v2;
}

// ---------------------------------------------------------------------------
// K2c: add bucket bases into per-block bases; also row_ptr[n] = e.
// ---------------------------------------------------------------------------
__global__ void add_bases_kernel(int* __restrict__ base_col, int* __restrict__ base_row,
                                 const int* __restrict__ bb_col, const int* __restrict__ bb_row,
                                 int* __restrict__ row_ptr, int n, int e, int nblk, int nb) {
    int side = (blockIdx.x >= (unsigned)nb) ? 1 : 0;
    int b = blockIdx.x - side * nb;
    int* base = side ? base_row : base_col;
    int add   = side ? bb_row[b] : bb_col[b];
    for (int t = threadIdx.x; t < nblk; t += blockDim.x) base[(size_t)t * nb + b] += add;
    if (blockIdx.x == 0 && threadIdx.x == 0) row_ptr[n] = e;
}

// ---------------------------------------------------------------------------
// K3: scatter edges into bucket-major temps via LDS cursors (no global atomics)
// tmp_col: int4 (col, row, ppmi_bits, 0); tmp_row: int2 (row, ppmi_bits)
// ---------------------------------------------------------------------------
__global__ void part_scatter_kernel(const int* __restrict__ row, const int* __restrict__ col,
                                    const float* __restrict__ ppmi,
                                    const int* __restrict__ base_col, const int* __restrict__ base_row,
                                    int4* __restrict__ tmp_col, int2* __restrict__ tmp_row,
                                    int e, int nb) {
    __shared__ int cc[256], cr[256];
    int t = threadIdx.x;
    if (t < nb) {
        cc[t] = base_col[blockIdx.x * nb + t];
        cr[t] = base_row[blockIdx.x * nb + t];
    }
    __syncthreads();
    int base = blockIdx.x * EPB;
    int lim  = min(EPB, e - base);
    for (int i = t; i < lim; i += 256) {
        int r = row[base + i], c = col[base + i];
        int w = __float_as_int(ppmi[base + i]);
        int sc = atomicAdd(&cc[c >> 9], 1);
        tmp_col[sc] = make_int4(c, r, w, 0);
        int sr = atomicAdd(&cr[r >> 9], 1);
        tmp_row[sr] = make_int2(r, w);
    }
}

// ---------------------------------------------------------------------------
// K4b: per-row-bucket degree accumulation in LDS (float LDS atomics), -> dis
// ---------------------------------------------------------------------------
__global__ void deg_bucket_kernel(const int2* __restrict__ tmp_row,
                                  const int* __restrict__ bb_row, const int* __restrict__ tot_row,
                                  float* __restrict__ dis_g, float* __restrict__ dis_p, int n) {
    __shared__ float dg[BKT], dp[BKT];
    int t = threadIdx.x;
    for (int j = t; j < BKT; j += 256) { dg[j] = 1.0f; dp[j] = 1.0f; }  // self-loop
    __syncthreads();
    int b = blockIdx.x;
    int beg = bb_row[b], cnt = tot_row[b];
    for (int i = t; i < cnt; i += 256) {
        int2 cell = tmp_row[beg + i];
        int lr = cell.x & (BKT - 1);
        atomicAdd(&dg[lr], 1.0f);
        atomicAdd(&dp[lr], __int_as_float(cell.y));
    }
    __syncthreads();
    int rb = b << 9;
    for (int j = t; j < BKT; j += 256) {
        int g = rb + j;
        if (g < n) {
            dis_g[g] = rsqrtf(dg[j]);
            dis_p[g] = rsqrtf(dp[j]);
        }
    }
}

// ---------------------------------------------------------------------------
// K4: per-col-bucket CSR finalize: LDS hist + scan -> row_ptr, LDS cursors ->
// csr fill with weights (dis gathers are L2-resident). 512 threads.
// ---------------------------------------------------------------------------
__launch_bounds__(512)
__global__ void csr_bucket_kernel(const int4* __restrict__ tmp_col,
                                  const int* __restrict__ bb_col, const int* __restrict__ tot_col,
                                  const float* __restrict__ dis_g, const float* __restrict__ dis_p,
                                  int* __restrict__ row_ptr, int* __restrict__ csr_src,
                                  float* __restrict__ csr_wg, float* __restrict__ csr_wp, int n) {
    __shared__ int hist[BKT], s[BKT], cur[BKT];
    int t = threadIdx.x;   // 512 threads
    hist[t] = 0;
    __syncthreads();
    int b = blockIdx.x;
    int beg = bb_col[b], cnt = tot_col[b];
    for (int i = t; i < cnt; i += BKT) atomicAdd(&hist[tmp_col[beg + i].x & (BKT - 1)], 1);
    __syncthreads();
    int own = hist[t];
    s[t] = own;
    __syncthreads();
    for (int off = 1; off < BKT; off <<= 1) {
        int v = (t >= off) ? s[t - off] : 0;
        __syncthreads();
        s[t] += v;
        __syncthreads();
    }
    int gslot = beg + s[t] - own;     // global CSR slot base for local col t
    cur[t] = gslot;
    int gc = (b << 9) + t;
    if (gc < n) row_ptr[gc] = gslot;
    __syncthreads();
    for (int i = t; i < cnt; i += BKT) {
        int4 cell = tmp_col[beg + i];
        int lc = cell.x & (BKT - 1);
        int slot = atomicAdd(&cur[lc], 1);
        int r = cell.y;
        float w = __int_as_float(cell.z);
        csr_src[slot] = r;
        csr_wg[slot]  = dis_g[r];
        csr_wp[slot]  = dis_p[r] * w;
    }
}

// ---------------------------------------------------------------------------
// W -> B^T split-bf16 prep
// ---------------------------------------------------------------------------
__global__ void conv_w_kernel(const float* __restrict__ W, __bf16* __restrict__ Bh,
                              __bf16* __restrict__ Bl, int K, int N) {
    int i = blockIdx.x * blockDim.x + threadIdx.x;
    if (i >= K * N) return;
    int k = i / N, nn = i % N;
    float v = W[i];
    __bf16 h = (__bf16)v;
    Bh[(size_t)nn * K + k] = h;
    Bl[(size_t)nn * K + k] = (__bf16)(v - (float)h);
}

// ---------------------------------------------------------------------------
// Split-bf16 MFMA GEMM: C[M,BN] = A[M,K] @ B[K,BN]
// ---------------------------------------------------------------------------
template<int BM, int BN>
__launch_bounds__(256, 2)
__global__ void mfma_gemm_kernel(const float* __restrict__ A,
                                 const __bf16* __restrict__ Bth, const __bf16* __restrict__ Btl,
                                 float* __restrict__ C, int M, int K) {
    constexpr int BK  = 32;
    constexpr int LDK = BK + 8;
    constexpr int WM  = BM / 4;
    constexpr int MT  = WM / 16;
    constexpr int NT  = BN / 16;
    __shared__ __bf16 Ash[BM * LDK];
    __shared__ __bf16 Asl[BM * LDK];
    __shared__ __bf16 Bsh[BN * LDK];
    __shared__ __bf16 Bsl[BN * LDK];

    const int tid  = threadIdx.x;
    const int wave = tid >> 6;
    const int lane = tid & 63;
    const int quad = lane >> 4;
    const int l16  = lane & 15;
    const int row0 = blockIdx.x * BM;

    f32x4 acc[MT][NT] = {};

    for (int k0 = 0; k0 < K; k0 += BK) {
#pragma unroll
        for (int p = 0; p < BM / 32; ++p) {
            int lin = p * 256 + tid;
            int r   = lin >> 3;
            int kc  = (lin & 7) * 4;
            int gr  = row0 + r;
            float4 v;
            if (gr < M) v = *(const float4*)(A + (size_t)gr * K + k0 + kc);
            else        v = make_float4(0.f, 0.f, 0.f, 0.f);
            __bf16 h0 = (__bf16)v.x, h1 = (__bf16)v.y, h2 = (__bf16)v.z, h3 = (__bf16)v.w;
            __bf16 l0 = (__bf16)(v.x - (float)h0), l1 = (__bf16)(v.y - (float)h1);
            __bf16 l2 = (__bf16)(v.z - (float)h2), l3 = (__bf16)(v.w - (float)h3);
            *(bf16x4*)&Ash[r * LDK + kc] = (bf16x4){h0, h1, h2, h3};
            *(bf16x4*)&Asl[r * LDK + kc] = (bf16x4){l0, l1, l2, l3};
        }
#pragma unroll
        for (int p = 0; p < BN / 64; ++p) {
            int lin = p * 256 + tid;
            int r   = lin >> 2;
            int kc  = (lin & 3) * 8;
            *(uint4*)&Bsh[r * LDK + kc] = *(const uint4*)(Bth + (size_t)r * K + k0 + kc);
            *(uint4*)&Bsl[r * LDK + kc] = *(const uint4*)(Btl + (size_t)r * K + k0 + kc);
        }
        __syncthreads();

        bf16x8 bh[NT], bl[NT];
#pragma unroll
        for (int j = 0; j < NT; ++j) {
            bh[j] = *(const bf16x8*)&Bsh[(j * 16 + l16) * LDK + quad * 8];
            bl[j] = *(const bf16x8*)&Bsl[(j * 16 + l16) * LDK + quad * 8];
        }
#pragma unroll
        for (int i = 0; i < MT; ++i) {
            int m = wave * WM + i * 16 + l16;
            bf16x8 ah = *(const bf16x8*)&Ash[m * LDK + quad * 8];
            bf16x8 al = *(const bf16x8*)&Asl[m * LDK + quad * 8];
#pragma unroll
            for (int j = 0; j < NT; ++j) {
                acc[i][j] = __builtin_amdgcn_mfma_f32_16x16x32_bf16(ah, bh[j], acc[i][j], 0, 0, 0);
                acc[i][j] = __builtin_amdgcn_mfma_f32_16x16x32_bf16(ah, bl[j], acc[i][j], 0, 0, 0);
                acc[i][j] = __builtin_amdgcn_mfma_f32_16x16x32_bf16(al, bh[j], acc[i][j], 0, 0, 0);
            }
        }
        __syncthreads();
    }

#pragma unroll
    for (int i = 0; i < MT; ++i) {
#pragma unroll
        for (int rg = 0; rg < 4; ++rg) {
            int gr = row0 + wave * WM + i * 16 + quad * 4 + rg;
            if (gr < M) {
#pragma unroll
                for (int j = 0; j < NT; ++j)
                    C[(size_t)gr * BN + j * 16 + l16] = acc[i][j][rg];
            }
        }
    }
}

// ---------------------------------------------------------------------------
// Layer-1 pull aggregation: one wave per node, float2 per lane (128 feats).
// ---------------------------------------------------------------------------
__global__ void agg1_pull_kernel(const int* __restrict__ row_ptr, const int* __restrict__ csr_src,
                                 const float* __restrict__ csr_wg, const float* __restrict__ csr_wp,
                                 const float* __restrict__ hw1,
                                 const float* __restrict__ dis_g, const float* __restrict__ dis_p,
                                 const float* __restrict__ b1,
                                 float* __restrict__ g_out, float* __restrict__ p_out, int n) {
    int c    = blockIdx.x * 4 + (threadIdx.x >> 6);
    int lane = threadIdx.x & 63;
    if (c >= n) return;
    int beg = row_ptr[c], end = row_ptr[c + 1];
    int f2 = lane * 2;
    float sgx = 0.f, sgy = 0.f, spx = 0.f, spy = 0.f;
    int t = beg;
    for (; t + 2 <= end; t += 2) {
        int r0 = csr_src[t], r1 = csr_src[t + 1];
        float wg0 = csr_wg[t], wg1 = csr_wg[t + 1];
        float wp0 = csr_wp[t], wp1 = csr_wp[t + 1];
        float2 h0 = *(const float2*)&hw1[(size_t)r0 * HH + f2];
        float2 h1 = *(const float2*)&hw1[(size_t)r1 * HH + f2];
        sgx += wg0 * h0.x + wg1 * h1.x;
        sgy += wg0 * h0.y + wg1 * h1.y;
        spx += wp0 * h0.x + wp1 * h1.x;
        spy += wp0 * h0.y + wp1 * h1.y;
    }
    if (t < end) {
        int r0 = csr_src[t];
        float wg0 = csr_wg[t], wp0 = csr_wp[t];
        float2 h0 = *(const float2*)&hw1[(size_t)r0 * HH + f2];
        sgx += wg0 * h0.x; sgy += wg0 * h0.y;
        spx += wp0 * h0.x; spy += wp0 * h0.y;
    }
    float dgc = dis_g[c], dpc = dis_p[c];
    size_t idx = (size_t)c * HH + f2;
    float2 hs = *(const float2*)&hw1[idx];
    float bx = b1[f2], by = b1[f2 + 1];
    float gx = dgc * sgx + dgc * dgc * hs.x + bx;
    float gy = dgc * sgy + dgc * dgc * hs.y + by;
    float px = dpc * spx + dpc * dpc * hs.x + bx;
    float py = dpc * spy + dpc * dpc * hs.y + by;
    float2 go, po;
    go.x = gx > 0.f ? gx : 0.f;  go.y = gy > 0.f ? gy : 0.f;
    po.x = px > 0.f ? px : 0.f;  po.y = py > 0.f ? py : 0.f;
    *(float2*)&g_out[idx] = go;
    *(float2*)&p_out[idx] = po;
}

// ---------------------------------------------------------------------------
// Layer-2 pull aggregation + self-loop + bias + softmax gate, fused.
// ---------------------------------------------------------------------------
__global__ void agg2_final_kernel(const int* __restrict__ row_ptr, const int* __restrict__ csr_src,
                                  const float* __restrict__ csr_wg, const float* __restrict__ csr_wp,
                                  const float* __restrict__ hw2_g, const float* __restrict__ hw2_p,
                                  const float* __restrict__ dis_g, const float* __restrict__ dis_p,
                                  const float* __restrict__ b2,
                                  const float* __restrict__ dense_w, const float* __restrict__ dense_b,
                                  float* __restrict__ out, int n) {
    int c = blockIdx.x * 4 + (threadIdx.x >> 6);
    int f = threadIdx.x & 63;
    if (c >= n) return;
    int beg = row_ptr[c], end = row_ptr[c + 1];
    float sg = 0.f, sp = 0.f;
    int t = beg;
    for (; t + 2 <= end; t += 2) {
        int r0 = csr_src[t], r1 = csr_src[t + 1];
        float wg0 = csr_wg[t], wg1 = csr_wg[t + 1];
        float wp0 = csr_wp[t], wp1 = csr_wp[t + 1];
        float hg0 = hw2_g[(size_t)r0 * OO + f], hg1 = hw2_g[(size_t)r1 * OO + f];
        float hp0 = hw2_p[(size_t)r0 * OO + f], hp1 = hw2_p[(size_t)r1 * OO + f];
        sg += wg0 * hg0 + wg1 * hg1;
        sp += wp0 * hp0 + wp1 * hp1;
    }
    if (t < end) {
        int r0 = csr_src[t];
        sg += csr_wg[t] * hw2_g[(size_t)r0 * OO + f];
        sp += csr_wp[t] * hw2_p[(size_t)r0 * OO + f];
    }
    float dgc = dis_g[c], dpc = dis_p[c];
    size_t idx = (size_t)c * OO + f;
    float bb = b2[f];
    float gv = dgc * sg + dgc * dgc * hw2_g[idx] + bb;
    float pv = dpc * sp + dpc * dpc * hw2_p[idx] + bb;
    float dw = dense_w[f];
    float lg = gv * dw, lp = pv * dw;
#pragma unroll
    for (int off = 32; off > 0; off >>= 1) {
        lg += __shfl_xor(lg, off, 64);
        lp += __shfl_xor(lp, off, 64);
    }
    lg += dense_b[0];
    lp += dense_b[0];
    float m  = fmaxf(lg, lp);
    float eg = expf(lg - m), ep = expf(lp - m);
    float wgt = eg / (eg + ep);
    out[idx] = wgt * gv + (1.0f - wgt) * pv;
}

// ---------------------------------------------------------------------------
extern "C" void kernel_launch(void* const* d_in, const int* in_sizes, int n_in,
                              void* d_out, int out_size, void* d_ws, size_t ws_size,
                              hipStream_t stream) {
    const float* x    = (const float*)d_in[0];
    const int*   ei   = (const int*)d_in[1];
    const float* ppmi = (const float*)d_in[2];
    const float* W1   = (const float*)d_in[3];
    const float* b1   = (const float*)d_in[4];
    const float* W2   = (const float*)d_in[5];
    const float* b2   = (const float*)d_in[6];
    const float* dw   = (const float*)d_in[7];
    const float* db   = (const float*)d_in[8];
    float* out = (float*)d_out;

    const int n = in_sizes[0] / DD;       // 100000
    const int e = in_sizes[2];            // 1600000
    const int* row = ei;
    const int* col = ei + e;

    const int nb   = (n + BKT - 1) / BKT;   // 196 buckets (<=256 required)
    const int nblk = (e + EPB - 1) / EPB;   // 196 partition blocks (<=256 required)

    // ---- workspace layout (floats unless noted) ----
    float* ws     = (float*)d_ws;
    float* dis_g  = ws;                              // n
    float* dis_p  = dis_g + n;                       // n
    float* hw1    = dis_p + n;                       // 128n (reused as hw2[2n*64])
    float* g1     = hw1 + (size_t)n * HH;            // 128n (tmp_col aliases: 4e ints)
    float* p1     = g1  + (size_t)n * HH;            // 128n (tmp_row aliases: 2e ints)
    float* csr_wg = p1  + (size_t)n * HH;            // e
    float* csr_wp = csr_wg + e;                      // e
    __bf16* bt1h  = (__bf16*)(csr_wp + e);           // DD*HH
    __bf16* bt1l  = bt1h + (size_t)DD * HH;
    __bf16* bt2h  = bt1l + (size_t)DD * HH;          // HH*OO
    __bf16* bt2l  = bt2h + (size_t)HH * OO;
    int* row_ptr  = (int*)(bt2l + (size_t)HH * OO);  // n+1
    int* csr_src  = row_ptr + (n + 1);               // e
    int* cnt_col  = csr_src + e;                     // nblk*nb
    int* base_col = cnt_col + (size_t)nblk * nb;     // nblk*nb
    int* cnt_row  = base_col + (size_t)nblk * nb;    // nblk*nb
    int* base_row = cnt_row + (size_t)nblk * nb;     // nblk*nb
    int* bb_col   = base_row + (size_t)nblk * nb;    // nb
    int* tot_col  = bb_col + nb;                     // nb
    int* bb_row   = tot_col + nb;                    // nb
    int* tot_row  = bb_row + nb;                     // nb
    int4* tmp_col = (int4*)g1;                       // e (alias, dead before agg1 writes g1)
    int2* tmp_row = (int2*)p1;                       // e (alias, dead before agg1 writes p1)
    float* hw2    = hw1;                             // [2n x 64]
    float* hw2_g  = hw2;
    float* hw2_p  = hw2 + (size_t)n * OO;

    const int T = 256;

    // ---- partition pipeline (LDS atomics only, fully parallel scans) ----
    part_count_kernel<<<nblk, T, 0, stream>>>(row, col, e, nb, cnt_col, cnt_row);
    scan_blocks_kernel<<<2 * nb, T, 0, stream>>>(cnt_col, cnt_row, base_col, base_row,
                                                 tot_col, tot_row, nblk, nb);
    scan_tots_kernel<<<1, T, 0, stream>>>(tot_col, tot_row, bb_col, bb_row, nb);
    add_bases_kernel<<<2 * nb, T, 0, stream>>>(base_col, base_row, bb_col, bb_row,
                                               row_ptr, n, e, nblk, nb);
    part_scatter_kernel<<<nblk, T, 0, stream>>>(row, col, ppmi, base_col, base_row,
                                                tmp_col, tmp_row, e, nb);
    deg_bucket_kernel<<<nb, T, 0, stream>>>(tmp_row, bb_row, tot_row, dis_g, dis_p, n);
    csr_bucket_kernel<<<nb, BKT, 0, stream>>>(tmp_col, bb_col, tot_col, dis_g, dis_p,
                                              row_ptr, csr_src, csr_wg, csr_wp, n);

    // ---- weight prep ----
    conv_w_kernel<<<(DD * HH + T - 1) / T, T, 0, stream>>>(W1, bt1h, bt1l, DD, HH);
    conv_w_kernel<<<(HH * OO + T - 1) / T, T, 0, stream>>>(W2, bt2h, bt2l, HH, OO);

    // ---- network ----
    mfma_gemm_kernel<128, HH><<<(n + 127) / 128, 256, 0, stream>>>(x, bt1h, bt1l, hw1, n, DD);
    agg1_pull_kernel<<<(n + 3) / 4, 256, 0, stream>>>(row_ptr, csr_src, csr_wg, csr_wp,
                                                      hw1, dis_g, dis_p, b1, g1, p1, n);
    mfma_gemm_kernel<128, OO><<<(2 * n + 127) / 128, 256, 0, stream>>>(g1, bt2h, bt2l, hw2, 2 * n, HH);
    agg2_final_kernel<<<(n + 3) / 4, 256, 0, stream>>>(row_ptr, csr_src, csr_wg, csr_wp,
                                                       hw2_g, hw2_p, dis_g, dis_p, b2, dw, db, out, n);
}

// Round 6
// 625.424 us; speedup vs baseline: 1.3913x; 1.0821x over previous
//
#include <hip/hip_runtime.h>
#include <hip/hip_bf16.h>
#include <math.h>

#define DD 256
#define HH 128
#define OO 64

#define EPB 8192          // edges per partition block
#define BKT 512           // nodes per bucket (bucket = idx >> 9)

typedef __attribute__((ext_vector_type(8))) __bf16 bf16x8;
typedef __attribute__((ext_vector_type(4))) __bf16 bf16x4;
typedef __attribute__((ext_vector_type(4))) float f32x4;

__device__ inline float2 bf2_to_f2(unsigned u) {
    float2 r;
    r.x = __uint_as_float(u << 16);
    r.y = __uint_as_float(u & 0xffff0000u);
    return r;
}

// ---------------------------------------------------------------------------
// K1: per-block LDS histograms over coarse buckets (both col and row sides)
// ---------------------------------------------------------------------------
__global__ void part_count_kernel(const int* __restrict__ row, const int* __restrict__ col,
                                  int e, int nb,
                                  int* __restrict__ cnt_col, int* __restrict__ cnt_row) {
    __shared__ int hc[256], hr[256];
    int t = threadIdx.x;
    hc[t] = 0; hr[t] = 0;
    __syncthreads();
    int base = blockIdx.x * EPB;
    int lim  = min(EPB, e - base);
    for (int i = t; i < lim; i += 256) {
        atomicAdd(&hc[col[base + i] >> 9], 1);
        atomicAdd(&hr[row[base + i] >> 9], 1);
    }
    __syncthreads();
    if (t < nb) {
        cnt_col[blockIdx.x * nb + t] = hc[t];
        cnt_row[blockIdx.x * nb + t] = hr[t];
    }
}

// ---------------------------------------------------------------------------
// K2a: one block per (side,bucket): scan nblk per-block counts -> bases+total
// ---------------------------------------------------------------------------
__global__ void scan_blocks_kernel(const int* __restrict__ cnt_col, const int* __restrict__ cnt_row,
                                   int* __restrict__ base_col, int* __restrict__ base_row,
                                   int* __restrict__ tot_col, int* __restrict__ tot_row,
                                   int nblk, int nb) {
    __shared__ int s[256];
    int side = (blockIdx.x >= (unsigned)nb) ? 1 : 0;
    int b = blockIdx.x - side * nb;
    const int* cnt = side ? cnt_row : cnt_col;
    int* base = side ? base_row : base_col;
    int* tot  = side ? tot_row  : tot_col;
    int t = threadIdx.x;
    int v = (t < nblk) ? cnt[(size_t)t * nb + b] : 0;
    s[t] = v;
    __syncthreads();
    for (int off = 1; off < 256; off <<= 1) {
        int u = (t >= off) ? s[t - off] : 0;
        __syncthreads();
        s[t] += u;
        __syncthreads();
    }
    if (t < nblk) base[(size_t)t * nb + b] = s[t] - v;
    if (t == 255) tot[b] = s[255];
}

// ---------------------------------------------------------------------------
// K2b: one block: exclusive scan of both totals arrays -> bucket bases
// ---------------------------------------------------------------------------
__global__ void scan_tots_kernel(const int* __restrict__ tot_col, const int* __restrict__ tot_row,
                                 int* __restrict__ bb_col, int* __restrict__ bb_row, int nb) {
    __shared__ int s[256];
    int t = threadIdx.x;
    int v = (t < nb) ? tot_col[t] : 0;
    s[t] = v;
    __syncthreads();
    for (int off = 1; off < 256; off <<= 1) {
        int u = (t >= off) ? s[t - off] : 0;
        __syncthreads();
        s[t] += u;
        __syncthreads();
    }
    if (t < nb) bb_col[t] = s[t] - v;
    __syncthreads();
    int v2 = (t < nb) ? tot_row[t] : 0;
    s[t] = v2;
    __syncthreads();
    for (int off = 1; off < 256; off <<= 1) {
        int u = (t >= off) ? s[t - off] : 0;
        __syncthreads();
        s[t] += u;
        __syncthreads();
    }
    if (t < nb) bb_row[t] = s[t] - v2;
}

// ---------------------------------------------------------------------------
// K2c: add bucket bases into per-block bases; also row_ptr[n] = e
// ---------------------------------------------------------------------------
__global__ void add_bases_kernel(int* __restrict__ base_col, int* __restrict__ base_row,
                                 const int* __restrict__ bb_col, const int* __restrict__ bb_row,
                                 int* __restrict__ row_ptr, int n, int e, int nblk, int nb) {
    int side = (blockIdx.x >= (unsigned)nb) ? 1 : 0;
    int b = blockIdx.x - side * nb;
    int* base = side ? base_row : base_col;
    int add   = side ? bb_row[b] : bb_col[b];
    for (int t = threadIdx.x; t < nblk; t += blockDim.x) base[(size_t)t * nb + b] += add;
    if (blockIdx.x == 0 && threadIdx.x == 0) row_ptr[n] = e;
}

// ---------------------------------------------------------------------------
// K3: scatter edges into bucket-major temps via LDS cursors
// ---------------------------------------------------------------------------
__global__ void part_scatter_kernel(const int* __restrict__ row, const int* __restrict__ col,
                                    const float* __restrict__ ppmi,
                                    const int* __restrict__ base_col, const int* __restrict__ base_row,
                                    int4* __restrict__ tmp_col, int2* __restrict__ tmp_row,
                                    int e, int nb) {
    __shared__ int cc[256], cr[256];
    int t = threadIdx.x;
    if (t < nb) {
        cc[t] = base_col[blockIdx.x * nb + t];
        cr[t] = base_row[blockIdx.x * nb + t];
    }
    __syncthreads();
    int base = blockIdx.x * EPB;
    int lim  = min(EPB, e - base);
    for (int i = t; i < lim; i += 256) {
        int r = row[base + i], c = col[base + i];
        int w = __float_as_int(ppmi[base + i]);
        int sc = atomicAdd(&cc[c >> 9], 1);
        tmp_col[sc] = make_int4(c, r, w, 0);
        int sr = atomicAdd(&cr[r >> 9], 1);
        tmp_row[sr] = make_int2(r, w);
    }
}

// ---------------------------------------------------------------------------
// K4b: per-row-bucket degree accumulation in LDS -> dis
// ---------------------------------------------------------------------------
__global__ void deg_bucket_kernel(const int2* __restrict__ tmp_row,
                                  const int* __restrict__ bb_row, const int* __restrict__ tot_row,
                                  float* __restrict__ dis_g, float* __restrict__ dis_p, int n) {
    __shared__ float dg[BKT], dp[BKT];
    int t = threadIdx.x;
    for (int j = t; j < BKT; j += 256) { dg[j] = 1.0f; dp[j] = 1.0f; }  // self-loop
    __syncthreads();
    int b = blockIdx.x;
    int beg = bb_row[b], cnt = tot_row[b];
    for (int i = t; i < cnt; i += 256) {
        int2 cell = tmp_row[beg + i];
        int lr = cell.x & (BKT - 1);
        atomicAdd(&dg[lr], 1.0f);
        atomicAdd(&dp[lr], __int_as_float(cell.y));
    }
    __syncthreads();
    int rb = b << 9;
    for (int j = t; j < BKT; j += 256) {
        int g = rb + j;
        if (g < n) {
            dis_g[g] = rsqrtf(dg[j]);
            dis_p[g] = rsqrtf(dp[j]);
        }
    }
}

// ---------------------------------------------------------------------------
// K4: per-col-bucket CSR finalize
// ---------------------------------------------------------------------------
__launch_bounds__(512)
__global__ void csr_bucket_kernel(const int4* __restrict__ tmp_col,
                                  const int* __restrict__ bb_col, const int* __restrict__ tot_col,
                                  const float* __restrict__ dis_g, const float* __restrict__ dis_p,
                                  int* __restrict__ row_ptr, int* __restrict__ csr_src,
                                  float* __restrict__ csr_wg, float* __restrict__ csr_wp, int n) {
    __shared__ int hist[BKT], s[BKT], cur[BKT];
    int t = threadIdx.x;   // 512 threads
    hist[t] = 0;
    __syncthreads();
    int b = blockIdx.x;
    int beg = bb_col[b], cnt = tot_col[b];
    for (int i = t; i < cnt; i += BKT) atomicAdd(&hist[tmp_col[beg + i].x & (BKT - 1)], 1);
    __syncthreads();
    int own = hist[t];
    s[t] = own;
    __syncthreads();
    for (int off = 1; off < BKT; off <<= 1) {
        int v = (t >= off) ? s[t - off] : 0;
        __syncthreads();
        s[t] += v;
        __syncthreads();
    }
    int gslot = beg + s[t] - own;
    cur[t] = gslot;
    int gc = (b << 9) + t;
    if (gc < n) row_ptr[gc] = gslot;
    __syncthreads();
    for (int i = t; i < cnt; i += BKT) {
        int4 cell = tmp_col[beg + i];
        int lc = cell.x & (BKT - 1);
        int slot = atomicAdd(&cur[lc], 1);
        int r = cell.y;
        float w = __int_as_float(cell.z);
        csr_src[slot] = r;
        csr_wg[slot]  = dis_g[r];
        csr_wp[slot]  = dis_p[r] * w;
    }
}

// ---------------------------------------------------------------------------
// W -> B^T split-bf16 prep
// ---------------------------------------------------------------------------
__global__ void conv_w_kernel(const float* __restrict__ W, __bf16* __restrict__ Bh,
                              __bf16* __restrict__ Bl, int K, int N) {
    int i = blockIdx.x * blockDim.x + threadIdx.x;
    if (i >= K * N) return;
    int k = i / N, nn = i % N;
    float v = W[i];
    __bf16 h = (__bf16)v;
    Bh[(size_t)nn * K + k] = h;
    Bl[(size_t)nn * K + k] = (__bf16)(v - (float)h);
}

// ---------------------------------------------------------------------------
// Split-bf16 MFMA GEMM: C[M,BN] = A[M,K] @ B[K,BN]; OT = fp32 or bf16 output.
// ---------------------------------------------------------------------------
template<int BM, int BN, typename OT>
__launch_bounds__(256, 2)
__global__ void mfma_gemm_kernel(const float* __restrict__ A,
                                 const __bf16* __restrict__ Bth, const __bf16* __restrict__ Btl,
                                 OT* __restrict__ C, int M, int K) {
    constexpr int BK  = 32;
    constexpr int LDK = BK + 8;
    constexpr int WM  = BM / 4;
    constexpr int MT  = WM / 16;
    constexpr int NT  = BN / 16;
    __shared__ __bf16 Ash[BM * LDK];
    __shared__ __bf16 Asl[BM * LDK];
    __shared__ __bf16 Bsh[BN * LDK];
    __shared__ __bf16 Bsl[BN * LDK];

    const int tid  = threadIdx.x;
    const int wave = tid >> 6;
    const int lane = tid & 63;
    const int quad = lane >> 4;
    const int l16  = lane & 15;
    const int row0 = blockIdx.x * BM;

    f32x4 acc[MT][NT] = {};

    for (int k0 = 0; k0 < K; k0 += BK) {
#pragma unroll
        for (int p = 0; p < BM / 32; ++p) {
            int lin = p * 256 + tid;
            int r   = lin >> 3;
            int kc  = (lin & 7) * 4;
            int gr  = row0 + r;
            float4 v;
            if (gr < M) v = *(const float4*)(A + (size_t)gr * K + k0 + kc);
            else        v = make_float4(0.f, 0.f, 0.f, 0.f);
            __bf16 h0 = (__bf16)v.x, h1 = (__bf16)v.y, h2 = (__bf16)v.z, h3 = (__bf16)v.w;
            __bf16 l0 = (__bf16)(v.x - (float)h0), l1 = (__bf16)(v.y - (float)h1);
            __bf16 l2 = (__bf16)(v.z - (float)h2), l3 = (__bf16)(v.w - (float)h3);
            *(bf16x4*)&Ash[r * LDK + kc] = (bf16x4){h0, h1, h2, h3};
            *(bf16x4*)&Asl[r * LDK + kc] = (bf16x4){l0, l1, l2, l3};
        }
#pragma unroll
        for (int p = 0; p < BN / 64; ++p) {
            int lin = p * 256 + tid;
            int r   = lin >> 2;
            int kc  = (lin & 3) * 8;
            *(uint4*)&Bsh[r * LDK + kc] = *(const uint4*)(Bth + (size_t)r * K + k0 + kc);
            *(uint4*)&Bsl[r * LDK + kc] = *(const uint4*)(Btl + (size_t)r * K + k0 + kc);
        }
        __syncthreads();

        bf16x8 bh[NT], bl[NT];
#pragma unroll
        for (int j = 0; j < NT; ++j) {
            bh[j] = *(const bf16x8*)&Bsh[(j * 16 + l16) * LDK + quad * 8];
            bl[j] = *(const bf16x8*)&Bsl[(j * 16 + l16) * LDK + quad * 8];
        }
#pragma unroll
        for (int i = 0; i < MT; ++i) {
            int m = wave * WM + i * 16 + l16;
            bf16x8 ah = *(const bf16x8*)&Ash[m * LDK + quad * 8];
            bf16x8 al = *(const bf16x8*)&Asl[m * LDK + quad * 8];
#pragma unroll
            for (int j = 0; j < NT; ++j) {
                acc[i][j] = __builtin_amdgcn_mfma_f32_16x16x32_bf16(ah, bh[j], acc[i][j], 0, 0, 0);
                acc[i][j] = __builtin_amdgcn_mfma_f32_16x16x32_bf16(ah, bl[j], acc[i][j], 0, 0, 0);
                acc[i][j] = __builtin_amdgcn_mfma_f32_16x16x32_bf16(al, bh[j], acc[i][j], 0, 0, 0);
            }
        }
        __syncthreads();
    }

#pragma unroll
    for (int i = 0; i < MT; ++i) {
#pragma unroll
        for (int rg = 0; rg < 4; ++rg) {
            int gr = row0 + wave * WM + i * 16 + quad * 4 + rg;
            if (gr < M) {
#pragma unroll
                for (int j = 0; j < NT; ++j)
                    C[(size_t)gr * BN + j * 16 + l16] = (OT)acc[i][j][rg];
            }
        }
    }
}

// ---------------------------------------------------------------------------
// Layer-1 pull aggregation: one wave per node; hw1 in bf16 (halved gather).
// ---------------------------------------------------------------------------
__global__ void agg1_pull_kernel(const int* __restrict__ row_ptr, const int* __restrict__ csr_src,
                                 const float* __restrict__ csr_wg, const float* __restrict__ csr_wp,
                                 const __bf16* __restrict__ hw1,
                                 const float* __restrict__ dis_g, const float* __restrict__ dis_p,
                                 const float* __restrict__ b1,
                                 float* __restrict__ g_out, float* __restrict__ p_out, int n) {
    int c    = blockIdx.x * 4 + (threadIdx.x >> 6);
    int lane = threadIdx.x & 63;
    if (c >= n) return;
    int beg = row_ptr[c], end = row_ptr[c + 1];
    int f2 = lane * 2;
    float sgx = 0.f, sgy = 0.f, spx = 0.f, spy = 0.f;
    int t = beg;
    for (; t + 2 <= end; t += 2) {
        int r0 = csr_src[t], r1 = csr_src[t + 1];
        float wg0 = csr_wg[t], wg1 = csr_wg[t + 1];
        float wp0 = csr_wp[t], wp1 = csr_wp[t + 1];
        float2 h0 = bf2_to_f2(*(const unsigned*)(hw1 + (size_t)r0 * HH + f2));
        float2 h1 = bf2_to_f2(*(const unsigned*)(hw1 + (size_t)r1 * HH + f2));
        sgx += wg0 * h0.x + wg1 * h1.x;
        sgy += wg0 * h0.y + wg1 * h1.y;
        spx += wp0 * h0.x + wp1 * h1.x;
        spy += wp0 * h0.y + wp1 * h1.y;
    }
    if (t < end) {
        int r0 = csr_src[t];
        float wg0 = csr_wg[t], wp0 = csr_wp[t];
        float2 h0 = bf2_to_f2(*(const unsigned*)(hw1 + (size_t)r0 * HH + f2));
        sgx += wg0 * h0.x; sgy += wg0 * h0.y;
        spx += wp0 * h0.x; spy += wp0 * h0.y;
    }
    float dgc = dis_g[c], dpc = dis_p[c];
    size_t idx = (size_t)c * HH + f2;
    float2 hs = bf2_to_f2(*(const unsigned*)(hw1 + idx));
    float bx = b1[f2], by = b1[f2 + 1];
    float gx = dgc * sgx + dgc * dgc * hs.x + bx;
    float gy = dgc * sgy + dgc * dgc * hs.y + by;
    float px = dpc * spx + dpc * dpc * hs.x + bx;
    float py = dpc * spy + dpc * dpc * hs.y + by;
    float2 go, po;
    go.x = gx > 0.f ? gx : 0.f;  go.y = gy > 0.f ? gy : 0.f;
    po.x = px > 0.f ? px : 0.f;  po.y = py > 0.f ? py : 0.f;
    *(float2*)&g_out[idx] = go;
    *(float2*)&p_out[idx] = po;
}

// ---------------------------------------------------------------------------
// Layer-2 pull aggregation + self-loop + bias + softmax gate; hw2 in bf16.
// ---------------------------------------------------------------------------
__global__ void agg2_final_kernel(const int* __restrict__ row_ptr, const int* __restrict__ csr_src,
                                  const float* __restrict__ csr_wg, const float* __restrict__ csr_wp,
                                  const __bf16* __restrict__ hw2_g, const __bf16* __restrict__ hw2_p,
                                  const float* __restrict__ dis_g, const float* __restrict__ dis_p,
                                  const float* __restrict__ b2,
                                  const float* __restrict__ dense_w, const float* __restrict__ dense_b,
                                  float* __restrict__ out, int n) {
    int c = blockIdx.x * 4 + (threadIdx.x >> 6);
    int f = threadIdx.x & 63;
    if (c >= n) return;
    int beg = row_ptr[c], end = row_ptr[c + 1];
    float sg = 0.f, sp = 0.f;
    int t = beg;
    for (; t + 2 <= end; t += 2) {
        int r0 = csr_src[t], r1 = csr_src[t + 1];
        float wg0 = csr_wg[t], wg1 = csr_wg[t + 1];
        float wp0 = csr_wp[t], wp1 = csr_wp[t + 1];
        float hg0 = (float)hw2_g[(size_t)r0 * OO + f], hg1 = (float)hw2_g[(size_t)r1 * OO + f];
        float hp0 = (float)hw2_p[(size_t)r0 * OO + f], hp1 = (float)hw2_p[(size_t)r1 * OO + f];
        sg += wg0 * hg0 + wg1 * hg1;
        sp += wp0 * hp0 + wp1 * hp1;
    }
    if (t < end) {
        int r0 = csr_src[t];
        sg += csr_wg[t] * (float)hw2_g[(size_t)r0 * OO + f];
        sp += csr_wp[t] * (float)hw2_p[(size_t)r0 * OO + f];
    }
    float dgc = dis_g[c], dpc = dis_p[c];
    size_t idx = (size_t)c * OO + f;
    float bb = b2[f];
    float gv = dgc * sg + dgc * dgc * (float)hw2_g[idx] + bb;
    float pv = dpc * sp + dpc * dpc * (float)hw2_p[idx] + bb;
    float dw = dense_w[f];
    float lg = gv * dw, lp = pv * dw;
#pragma unroll
    for (int off = 32; off > 0; off >>= 1) {
        lg += __shfl_xor(lg, off, 64);
        lp += __shfl_xor(lp, off, 64);
    }
    lg += dense_b[0];
    lp += dense_b[0];
    float m  = fmaxf(lg, lp);
    float eg = expf(lg - m), ep = expf(lp - m);
    float wgt = eg / (eg + ep);
    out[idx] = wgt * gv + (1.0f - wgt) * pv;
}

// ---------------------------------------------------------------------------
extern "C" void kernel_launch(void* const* d_in, const int* in_sizes, int n_in,
                              void* d_out, int out_size, void* d_ws, size_t ws_size,
                              hipStream_t stream) {
    const float* x    = (const float*)d_in[0];
    const int*   ei   = (const int*)d_in[1];
    const float* ppmi = (const float*)d_in[2];
    const float* W1   = (const float*)d_in[3];
    const float* b1   = (const float*)d_in[4];
    const float* W2   = (const float*)d_in[5];
    const float* b2   = (const float*)d_in[6];
    const float* dw   = (const float*)d_in[7];
    const float* db   = (const float*)d_in[8];
    float* out = (float*)d_out;

    const int n = in_sizes[0] / DD;       // 100000
    const int e = in_sizes[2];            // 1600000
    const int* row = ei;
    const int* col = ei + e;

    const int nb   = (n + BKT - 1) / BKT;   // buckets (<=256 required)
    const int nblk = (e + EPB - 1) / EPB;   // partition blocks (<=256 required)

    // ---- workspace layout ----
    float* ws     = (float*)d_ws;
    float* dis_g  = ws;                              // n f32
    float* dis_p  = dis_g + n;                       // n f32
    __bf16* hw1   = (__bf16*)(dis_p + n);            // 128n bf16 (aliased as hw2[2n*64] bf16)
    float* g1     = (float*)(hw1 + (size_t)n * HH);  // 128n f32 (tmp_col aliases: int4[e])
    float* p1     = g1  + (size_t)n * HH;            // 128n f32 (tmp_row aliases: int2[e])
    float* csr_wg = p1  + (size_t)n * HH;            // e
    float* csr_wp = csr_wg + e;                      // e
    __bf16* bt1h  = (__bf16*)(csr_wp + e);           // DD*HH
    __bf16* bt1l  = bt1h + (size_t)DD * HH;
    __bf16* bt2h  = bt1l + (size_t)DD * HH;          // HH*OO
    __bf16* bt2l  = bt2h + (size_t)HH * OO;
    int* row_ptr  = (int*)(bt2l + (size_t)HH * OO);  // n+1
    int* csr_src  = row_ptr + (n + 1);               // e
    int* cnt_col  = csr_src + e;                     // nblk*nb
    int* base_col = cnt_col + (size_t)nblk * nb;     // nblk*nb
    int* cnt_row  = base_col + (size_t)nblk * nb;    // nblk*nb
    int* base_row = cnt_row + (size_t)nblk * nb;     // nblk*nb
    int* bb_col   = base_row + (size_t)nblk * nb;    // nb
    int* tot_col  = bb_col + nb;                     // nb
    int* bb_row   = tot_col + nb;                    // nb
    int* tot_row  = bb_row + nb;                     // nb
    int4* tmp_col = (int4*)g1;                       // e (alias, dead before agg1 writes g1)
    int2* tmp_row = (int2*)p1;                       // e (alias, dead before agg1 writes p1)
    __bf16* hw2   = hw1;                             // [2n x 64] bf16
    __bf16* hw2_g = hw2;
    __bf16* hw2_p = hw2 + (size_t)n * OO;

    const int T = 256;

    // ---- partition pipeline (LDS atomics only, fully parallel scans) ----
    part_count_kernel<<<nblk, T, 0, stream>>>(row, col, e, nb, cnt_col, cnt_row);
    scan_blocks_kernel<<<2 * nb, T, 0, stream>>>(cnt_col, cnt_row, base_col, base_row,
                                                 tot_col, tot_row, nblk, nb);
    scan_tots_kernel<<<1, T, 0, stream>>>(tot_col, tot_row, bb_col, bb_row, nb);
    add_bases_kernel<<<2 * nb, T, 0, stream>>>(base_col, base_row, bb_col, bb_row,
                                               row_ptr, n, e, nblk, nb);
    part_scatter_kernel<<<nblk, T, 0, stream>>>(row, col, ppmi, base_col, base_row,
                                                tmp_col, tmp_row, e, nb);
    deg_bucket_kernel<<<nb, T, 0, stream>>>(tmp_row, bb_row, tot_row, dis_g, dis_p, n);
    csr_bucket_kernel<<<nb, BKT, 0, stream>>>(tmp_col, bb_col, tot_col, dis_g, dis_p,
                                              row_ptr, csr_src, csr_wg, csr_wp, n);

    // ---- weight prep ----
    conv_w_kernel<<<(DD * HH + T - 1) / T, T, 0, stream>>>(W1, bt1h, bt1l, DD, HH);
    conv_w_kernel<<<(HH * OO + T - 1) / T, T, 0, stream>>>(W2, bt2h, bt2l, HH, OO);

    // ---- network ----
    mfma_gemm_kernel<128, HH, __bf16><<<(n + 127) / 128, 256, 0, stream>>>(x, bt1h, bt1l, hw1, n, DD);
    agg1_pull_kernel<<<(n + 3) / 4, 256, 0, stream>>>(row_ptr, csr_src, csr_wg, csr_wp,
                                                      hw1, dis_g, dis_p, b1, g1, p1, n);
    mfma_gemm_kernel<128, OO, __bf16><<<(2 * n + 127) / 128, 256, 0, stream>>>(g1, bt2h, bt2l, hw2, 2 * n, HH);
    agg2_final_kernel<<<(n + 3) / 4, 256, 0, stream>>>(row_ptr, csr_src, csr_wg, csr_wp,
                                                       hw2_g, hw2_p, dis_g, dis_p, b2, dw, db, out, n);
}